// Round 11
// baseline (218.536 us; speedup 1.0000x reference)
//
#include <hip/hip_runtime.h>
#include <hip/hip_fp16.h>
#include <math.h>

// GCN forward, CSR-gather; bf16 xs/W2; MFMA layer-2 dense; block-
// aggregated pooling. CSR build = single-pass fixed-capacity bucket sort.
// R11: gather pipeline deepened 8->16 rows in flight (2 halves x 8-deep
// counted batches + next-batch col prefetch). Rationale: R10 counters
// (VALU 33%, HBM 16%, occ 65%, FETCH at 51.5MB compulsory floor) =
// latency-bound; R3's null on this lever was measured in the old
// fetch-throughput regime (149MB) so it doesn't refute the latency
// theory here. Pre-commit: if delta < 2us, MLP is null in both regimes
// -> gather is at a scheduling floor -> roofline call next round.
// R10: HW v_cvt_pk_f32_bf8 decode (bit-exact vs fp16-top-byte trick).
// R9: ht1 stored e5m2 -> FETCH 149->51.5MB (= 8 XCD x 6.4MB table).
// Requires N <= 65536 (src packed in 16 bits, bucket fits 8 bits).

#define BCAP 12288   // bucket capacity (mean fill ~8.2K, 45 sigma headroom)
#define TILE 8192    // bfill edges per block (LDS-staged, 64KB)

typedef __attribute__((ext_vector_type(8))) short short8;   // 8 bf16 (4 VGPRs)
typedef __attribute__((ext_vector_type(4))) float f32x4;    // MFMA accumulator
typedef __attribute__((ext_vector_type(2))) float f32x2;

__device__ __forceinline__ void bf4acc(uint2 u, float* a) {
    a[0] += __uint_as_float(u.x << 16);
    a[1] += __uint_as_float(u.x & 0xffff0000u);
    a[2] += __uint_as_float(u.y << 16);
    a[3] += __uint_as_float(u.y & 0xffff0000u);
}

__device__ __forceinline__ unsigned short bf1(float a) {    // RNE bf16
    unsigned ua = __float_as_uint(a);
    return (unsigned short)((ua + 0x7fffu + ((ua >> 16) & 1u)) >> 16);
}

__device__ __forceinline__ unsigned char e5m2q(float v) {   // RNE e5m2
    const unsigned hb = (unsigned)__half_as_ushort(__float2half(v));
    return (unsigned char)((hb + 0x7fu + ((hb >> 8) & 1u)) >> 8);
}

// decode 4 e5m2 bytes (features 4k..4k+3) and accumulate.
// bf8 (AMD) == e5m2 (OCP): HW cvt is bit-exact vs the fp16-top-byte trick.
__device__ __forceinline__ void e5acc(unsigned u, float* a) {
#if __has_builtin(__builtin_amdgcn_cvt_pk_f32_bf8)
    const f32x2 lo = __builtin_amdgcn_cvt_pk_f32_bf8((int)u, false);
    const f32x2 hi = __builtin_amdgcn_cvt_pk_f32_bf8((int)u, true);
    a[0] += lo[0]; a[1] += lo[1];
    a[2] += hi[0]; a[3] += hi[1];
#else
    unsigned h01 = ((u & 0x000000ffu) << 8) | ((u & 0x0000ff00u) << 16);
    unsigned h23 = ((u & 0x00ff0000u) >> 8) | (u & 0xff000000u);
    const __half2 x01 = *reinterpret_cast<const __half2*>(&h01);
    const __half2 x23 = *reinterpret_cast<const __half2*>(&h23);
    const float2 f01 = __half22float2(x01);
    const float2 f23 = __half22float2(x23);
    a[0] += f01.x; a[1] += f01.y;
    a[2] += f23.x; a[3] += f23.y;
#endif
}

// ---- LDS-staged bucketed fill: 8192-edge tile -> local counting sort ->
//      coalesced per-bucket run copy-out (~32 edges = 128B per run) ----
__global__ __launch_bounds__(512) void k_bfill(
        const int* __restrict__ ei, int* __restrict__ bcnt,
        unsigned* __restrict__ col1,
        const int* __restrict__ batch, int* __restrict__ gptr,
        float* __restrict__ gsum, const float* __restrict__ W2,
        unsigned short* __restrict__ W2bf,
        int E, int NB, int N, int G) {
    __shared__ unsigned ev[TILE];      // (b<<24)|(dstLocal<<16)|src
    __shared__ unsigned es[TILE];      // bucket-sorted
    __shared__ int bins[256], scn[256], cur[256], gbase[256];
    const int t = threadIdx.x;
    const int e0 = blockIdx.x * TILE;
    int cnt = E - e0; if (cnt > TILE) cnt = TILE;

    if (t < 256) bins[t] = 0;
    __syncthreads();
    for (int i = t; i < cnt; i += 512) {        // stage + histogram
        const int d = ei[E + e0 + i];
        const int s = ei[e0 + i];
        const unsigned b = (unsigned)d >> 8;    // NB <= 256 -> fits 8 bits
        ev[i] = (b << 24) | ((unsigned)(d & 255) << 16) | (unsigned)s;
        atomicAdd(&bins[b], 1);
    }
    __syncthreads();
    int v = 0;
    if (t < 256) { v = bins[t]; scn[t] = v; }
    __syncthreads();
    for (int off = 1; off < 256; off <<= 1) {   // inclusive scan (256-wide)
        int add = (t >= off && t < 256) ? scn[t - off] : 0;
        __syncthreads();
        if (t < 256) scn[t] += add;
        __syncthreads();
    }
    int ex = 0;
    if (t < 256) ex = scn[t] - v;
    __syncthreads();
    if (t < 256) {
        scn[t] = ex;                            // exclusive local offsets
        cur[t] = 0;
        gbase[t] = v ? atomicAdd(&bcnt[t], v) : 0;  // reserve global run
    }
    __syncthreads();
    for (int i = t; i < cnt; i += 512) {        // scatter within LDS
        const unsigned e = ev[i];
        const int b = e >> 24;
        const int p = scn[b] + atomicAdd(&cur[b], 1);
        es[p] = e;
    }
    __syncthreads();
    for (int i = t; i < cnt; i += 512) {        // coalesced copy-out
        const unsigned e = es[i];
        const int b = e >> 24;
        const int pos = gbase[b] + (i - scn[b]);
        if (pos < BCAP)
            col1[(size_t)b * BCAP + pos] = e & 0xffffffu;
    }

    // distributed prep tails
    const int gid = blockIdx.x * 512 + t;
    const int gsz = gridDim.x * 512;
    for (int i = gid; i < G * 32; i += gsz)        // gsum = 0 (float4)
        ((float4*)gsum)[i] = make_float4(0.f, 0.f, 0.f, 0.f);
    for (int i = gid; i < 16384; i += gsz) {       // W2bf[f2][f1] = bf16(W2[f1][f2])
        const int f2 = i >> 7, f1 = i & 127;
        W2bf[i] = bf1(W2[f1 * 128 + f2]);
    }
    for (int g = gid; g <= G; g += gsz) {          // gptr = lower_bound(batch,g)
        int lo = 0, hi = N;
        while (lo < hi) {
            int mid = (lo + hi) >> 1;
            if (batch[mid] < g) lo = mid + 1; else hi = mid;
        }
        gptr[g] = lo;
    }
}

// ---- per-bucket LDS sort -> exact CSR + dinv + xsb (self-scans bcnt) ----
__global__ __launch_bounds__(512) void k_bsort(const unsigned* __restrict__ col1,
                                               const int* __restrict__ bcnt,
                                               int* __restrict__ col,
                                               int* __restrict__ rowptr,
                                               float* __restrict__ dinv,
                                               const float* __restrict__ x,
                                               unsigned short* __restrict__ xsb,
                                               int N, int E, int NB) {
    __shared__ unsigned ec[BCAP];
    __shared__ int bins[256], sc[256];
    __shared__ float dvb[256];
    const int b = blockIdx.x, t = threadIdx.x;

    // bucket-offset scan (196 ints, L2-hot): s0 = sum_{i<b} bcnt[i]
    if (t < 256) bins[t] = (t < NB) ? bcnt[t] : 0;
    __syncthreads();
    for (int off = 1; off < 256; off <<= 1) {
        int add = (t >= off && t < 256) ? bins[t - off] : 0;
        __syncthreads();
        if (t < 256) bins[t] += add;
        __syncthreads();
    }
    const int s0 = (b == 0) ? 0 : bins[b - 1];
    int cnt = bcnt[b];
    if (cnt > BCAP) cnt = BCAP;        // safety clamp (never hit for this E,N)
    __syncthreads();

    for (int i = t; i < cnt; i += 512) ec[i] = col1[(size_t)b * BCAP + i];
    if (t < 256) bins[t] = 0;
    __syncthreads();
    for (int i = t; i < cnt; i += 512) atomicAdd(&bins[ec[i] >> 16], 1);
    __syncthreads();
    int v = 0;
    if (t < 256) { v = bins[t]; sc[t] = v; }
    __syncthreads();
    for (int off = 1; off < 256; off <<= 1) {
        int add = (t >= off && t < 256) ? sc[t - off] : 0;
        __syncthreads();
        if (t < 256) sc[t] += add;
        __syncthreads();
    }
    int ex = 0;
    if (t < 256) ex = sc[t] - v;
    __syncthreads();
    const int n0 = b * 256;
    if (t < 256) {
        sc[t] = ex;          // exclusive local offsets
        bins[t] = 0;         // reuse as per-node cursor
        const float dv = rsqrtf((float)(v + 1));
        dvb[t] = dv;
        if (n0 + t < N) {
            rowptr[n0 + t] = s0 + ex;
            dinv[n0 + t] = dv;
        }
    }
    if (b == 0 && t == 0) rowptr[N] = E;
    __syncthreads();
    for (int i = t; i < cnt; i += 512) {
        unsigned e = ec[i];
        int dl = e >> 16;
        int p = sc[dl] + atomicAdd(&bins[dl], 1);
        col[s0 + p] = (int)(e & 0xffffu);
    }
    // xsb = bf16(x * dinv) for this bucket's nodes (coalesced)
    int nn = N - n0; if (nn > 256) nn = 256;
    const int lim = nn * 16;
    for (int i = t; i < lim; i += 512) {
        float vx = x[(size_t)n0 * 16 + i] * dvb[i >> 4];
        xsb[(size_t)n0 * 16 + i] = bf1(vx);
    }
}

// ---- FUSED gat16 + l12 (MFMA): 64 nodes/block, 512 threads (8 waves),
//      ~57 KB LDS -> 2 blocks/CU. Epilogue stores ht1 as e5m2 bytes.
__global__ __launch_bounds__(512, 4) void k_l12g(
        const int* __restrict__ rowptr, const int* __restrict__ col,
        const unsigned short* __restrict__ xsb,
        const float* __restrict__ dinv,
        const float* __restrict__ W1, const float* __restrict__ b1,
        const unsigned short* __restrict__ W2bf,   // [f2][f1] bf16
        unsigned char* __restrict__ ht1q, int N) {
    __shared__ __align__(16) unsigned short W2s[128 * 136];  // [f2][f1] padded
    __shared__ __align__(16) unsigned short h1b[64 * 136];   // [node][f1] padded
    __shared__ __align__(16) float arow[64 * 16];
    __shared__ float dv[64];
    const int tid = threadIdx.x;
    const int n0 = blockIdx.x * 64;
    const int w = tid >> 6, lane = tid & 63;

    // stage W2^T (bf16): 128 rows x 16 uint4 segments
    for (int i = tid; i < 2048; i += 512) {
        const int f2 = i >> 4, seg = i & 15;
        *(uint4*)&W2s[f2 * 136 + seg * 8] = ((const uint4*)W2bf)[i];
    }
    if (tid < 64) dv[tid] = (n0 + tid < N) ? dinv[n0 + tid] : 0.f;

    // gather: 8 lanes per node (2 edge slots x 4 quarters), 8 nodes per wave
    {
        const int nd = lane >> 3, sub = lane & 7;
        const int slot = sub >> 2, qq = sub & 3;
        const int j = w * 8 + nd;
        const int n = n0 + j;
        float a[4] = {0.f, 0.f, 0.f, 0.f};
        if (n < N) {
            const int r1 = rowptr[n + 1];
            for (int e = rowptr[n] + slot; e < r1; e += 2)
                bf4acc(*(const uint2*)(xsb + (size_t)col[e] * 16 + qq * 4), a);
        }
#pragma unroll
        for (int i = 0; i < 4; ++i) a[i] += __shfl_xor(a[i], 4);
        if (slot == 0) {
            if (n < N) {   // self loop
                bf4acc(*(const uint2*)(xsb + (size_t)n * 16 + qq * 4), a);
                *(float4*)&arow[j * 16 + qq * 4] = make_float4(a[0], a[1], a[2], a[3]);
            } else {
                *(float4*)&arow[j * 16 + qq * 4] = make_float4(0.f, 0.f, 0.f, 0.f);
            }
        }
    }
    const int f = tid & 127, jg = tid >> 7;
    float w1r[16];
#pragma unroll
    for (int k = 0; k < 16; ++k) w1r[k] = W1[k * 128 + f];
    const float bias = b1[f];
    __syncthreads();

    // phase 1: h1 (bf16) into A-layout LDS
#pragma unroll 4
    for (int j = jg * 16; j < jg * 16 + 16; ++j) {
        float s = 0.f;
#pragma unroll
        for (int k = 0; k < 16; ++k) s += arow[j * 16 + k] * w1r[k];
        h1b[j * 136 + f] = bf1(fmaxf(dv[j] * s + bias, 0.f));
    }
    __syncthreads();

    // phase 2: MFMA, D[64x128] = h1[64x128] @ W2[128x128]
    const int mt = w & 3, nh = w >> 2;
    const int lm = lane & 15, quad = lane >> 4;
    f32x4 acc[4];
#pragma unroll
    for (int t = 0; t < 4; ++t) acc[t] = (f32x4){0.f, 0.f, 0.f, 0.f};
#pragma unroll
    for (int kb = 0; kb < 4; ++kb) {
        const short8 af = *(const short8*)&h1b[(mt * 16 + lm) * 136 + kb * 32 + quad * 8];
#pragma unroll
        for (int t = 0; t < 4; ++t) {
            const short8 bfv = *(const short8*)&W2s[(nh * 64 + t * 16 + lm) * 136 + kb * 32 + quad * 8];
            acc[t] = __builtin_amdgcn_mfma_f32_16x16x32_bf16(af, bfv, acc[t], 0, 0, 0);
        }
    }
    // epilogue: *dinv, quantize e5m2, store bytes
#pragma unroll
    for (int t = 0; t < 4; ++t) {
        const int f2 = nh * 64 + t * 16 + lm;
#pragma unroll
        for (int r = 0; r < 4; ++r) {
            const int j = mt * 16 + quad * 4 + r;
            const int n = n0 + j;
            if (n < N)
                ht1q[(size_t)n * 128 + f2] = e5m2q(acc[t][r] * dv[j]);
        }
    }
}

// Wave/node gather: 2 halves x 8-deep counted batches (16 rows/wave in
// flight), next-batch col prefetch issued before the accumulate waits.
// Then 8-node LDS run-merge (batch sorted) -> ~1 atomic set/block.
// Row = 128B e5m2; lane offset hoisted into hb.
__global__ __launch_bounds__(512) void k_gat128pool(
        const int* __restrict__ rowptr, const int* __restrict__ col,
        const unsigned char* __restrict__ ht1q,
        const float* __restrict__ dinv, const float* __restrict__ b2,
        const int* __restrict__ batch, float* __restrict__ gsum, int N) {
    __shared__ __align__(16) float h2s[8][128];
    __shared__ int bats[8];
    const int wave = threadIdx.x >> 6, lane = threadIdx.x & 63;
    const int half = lane >> 5, q = lane & 31;
    const int n = blockIdx.x * 8 + wave;
    const unsigned char* hb = ht1q + q * 4;    // lane's 4B column, hoisted
    float a[4] = {0.f, 0.f, 0.f, 0.f};
    if (n < N) {
        const int r0 = rowptr[n], r1 = rowptr[n + 1];
        int j = r0 + half;
        // edges this half handles: j, j+2, j+4, ... < r1
        const int cnt = (j < r1) ? (((r1 - 1 - j) >> 1) + 1) : 0;
        const int nb = cnt >> 3;       // full batches of 8 rows
        if (nb > 0) {
            int c0 = col[j],      c1 = col[j + 2],  c2 = col[j + 4],  c3 = col[j + 6];
            int c4 = col[j + 8],  c5 = col[j + 10], c6 = col[j + 12], c7 = col[j + 14];
            for (int b = 1; b < nb; ++b) {
                const unsigned u0 = *(const unsigned*)(hb + ((size_t)c0 << 7));
                const unsigned u1 = *(const unsigned*)(hb + ((size_t)c1 << 7));
                const unsigned u2 = *(const unsigned*)(hb + ((size_t)c2 << 7));
                const unsigned u3 = *(const unsigned*)(hb + ((size_t)c3 << 7));
                const unsigned u4 = *(const unsigned*)(hb + ((size_t)c4 << 7));
                const unsigned u5 = *(const unsigned*)(hb + ((size_t)c5 << 7));
                const unsigned u6 = *(const unsigned*)(hb + ((size_t)c6 << 7));
                const unsigned u7 = *(const unsigned*)(hb + ((size_t)c7 << 7));
                // next batch's cols (batch b <= nb-1 is full -> in-bounds)
                c0 = col[j + 16]; c1 = col[j + 18]; c2 = col[j + 20]; c3 = col[j + 22];
                c4 = col[j + 24]; c5 = col[j + 26]; c6 = col[j + 28]; c7 = col[j + 30];
                e5acc(u0, a); e5acc(u1, a); e5acc(u2, a); e5acc(u3, a);
                e5acc(u4, a); e5acc(u5, a); e5acc(u6, a); e5acc(u7, a);
                j += 16;
            }
            {   // final full batch (no prefetch)
                const unsigned u0 = *(const unsigned*)(hb + ((size_t)c0 << 7));
                const unsigned u1 = *(const unsigned*)(hb + ((size_t)c1 << 7));
                const unsigned u2 = *(const unsigned*)(hb + ((size_t)c2 << 7));
                const unsigned u3 = *(const unsigned*)(hb + ((size_t)c3 << 7));
                const unsigned u4 = *(const unsigned*)(hb + ((size_t)c4 << 7));
                const unsigned u5 = *(const unsigned*)(hb + ((size_t)c5 << 7));
                const unsigned u6 = *(const unsigned*)(hb + ((size_t)c6 << 7));
                const unsigned u7 = *(const unsigned*)(hb + ((size_t)c7 << 7));
                e5acc(u0, a); e5acc(u1, a); e5acc(u2, a); e5acc(u3, a);
                e5acc(u4, a); e5acc(u5, a); e5acc(u6, a); e5acc(u7, a);
                j += 16;
            }
        }
        while (j < r1) {               // tail: cnt mod 8 rows
            e5acc(*(const unsigned*)(hb + ((size_t)col[j] << 7)), a);
            j += 2;
        }
        if (half == 0)  // self loop
            e5acc(*(const unsigned*)(hb + ((size_t)n << 7)), a);
    }
#pragma unroll
    for (int i = 0; i < 4; ++i) a[i] += __shfl_xor(a[i], 32);
    if (half == 0) {
        if (n < N) {
            const float d = dinv[n];
            const float4 bb = *(const float4*)(b2 + q * 4);
            h2s[wave][q * 4 + 0] = fmaxf(a[0] * d + bb.x, 0.f);
            h2s[wave][q * 4 + 1] = fmaxf(a[1] * d + bb.y, 0.f);
            h2s[wave][q * 4 + 2] = fmaxf(a[2] * d + bb.z, 0.f);
            h2s[wave][q * 4 + 3] = fmaxf(a[3] * d + bb.w, 0.f);
            if (q == 0) bats[wave] = batch[n];
        } else {
            h2s[wave][q * 4 + 0] = 0.f; h2s[wave][q * 4 + 1] = 0.f;
            h2s[wave][q * 4 + 2] = 0.f; h2s[wave][q * 4 + 3] = 0.f;
            if (q == 0) bats[wave] = -1;
        }
    }
    __syncthreads();
    if (threadIdx.x < 32) {
        const int qq = threadIdx.x;
        int bprev = bats[0];
        float4 acc4 = *(const float4*)&h2s[0][qq * 4];
#pragma unroll
        for (int wv = 1; wv < 8; ++wv) {
            const int bw = bats[wv];   // wave-uniform branch (LDS scalar)
            const float4 rv = *(const float4*)&h2s[wv][qq * 4];
            if (bw == bprev) {
                acc4.x += rv.x; acc4.y += rv.y; acc4.z += rv.z; acc4.w += rv.w;
            } else {
                if (bprev >= 0) {
                    float* gs = gsum + (size_t)bprev * 128 + qq * 4;
                    unsafeAtomicAdd(gs + 0, acc4.x); unsafeAtomicAdd(gs + 1, acc4.y);
                    unsafeAtomicAdd(gs + 2, acc4.z); unsafeAtomicAdd(gs + 3, acc4.w);
                }
                bprev = bw; acc4 = rv;
            }
        }
        if (bprev >= 0) {
            float* gs = gsum + (size_t)bprev * 128 + qq * 4;
            unsafeAtomicAdd(gs + 0, acc4.x); unsafeAtomicAdd(gs + 1, acc4.y);
            unsafeAtomicAdd(gs + 2, acc4.z); unsafeAtomicAdd(gs + 3, acc4.w);
        }
    }
}

__global__ __launch_bounds__(128) void k_head(
        const float* __restrict__ gsum, const int* __restrict__ gptr,
        const float* __restrict__ Wlab, const float* __restrict__ blab,
        const float* __restrict__ Wd1, const float* __restrict__ bd1,
        const float* __restrict__ Wd2, const float* __restrict__ bd2,
        float* __restrict__ out, int G) {
    __shared__ float sp[128];
    __shared__ float red[128];
    __shared__ float hd[64];
    const int g = blockIdx.x, t = threadIdx.x;
    const float cnt = (float)(gptr[g + 1] - gptr[g]);
    const float invc = 1.f / fmaxf(cnt, 1.f);
    const float pooled = gsum[g * 128 + t] * invc;
    sp[t] = pooled;
    red[t] = pooled * Wlab[t];
    __syncthreads();
    for (int off = 64; off > 0; off >>= 1) {
        if (t < off) red[t] += red[t + off];
        __syncthreads();
    }
    if (t == 0) out[g] = 1.f / (1.f + expf(-(red[0] + blab[0])));
    __syncthreads();   // red[] reuse barrier (label reduce fully consumed)
    // domain hidden: 2-way split-K across all 128 threads
    const int tt = t & 63, kh = t >> 6;
    const int f0 = kh * 64;
    float ps = 0.f;
#pragma unroll 8
    for (int f = f0; f < f0 + 64; ++f) ps += sp[f] * Wd1[f * 64 + tt];
    red[t] = ps;
    __syncthreads();
    if (t < 64) hd[t] = fmaxf(red[t] + red[t + 64] + bd1[t], 0.f);
    __syncthreads();
    if (t < 2) {
        float s = bd2[t];
        for (int j = 0; j < 64; ++j) s += hd[j] * Wd2[j * 2 + t];
        out[G + g * 2 + t] = s;
    }
}

extern "C" void kernel_launch(void* const* d_in, const int* in_sizes, int n_in,
                              void* d_out, int out_size, void* d_ws, size_t ws_size,
                              hipStream_t stream) {
    const float* x     = (const float*)d_in[0];
    const int*   ei    = (const int*)d_in[1];   // [2,E]: ei[e]=src, ei[E+e]=dst
    const int*   batch = (const int*)d_in[2];
    const float* W1    = (const float*)d_in[3];
    const float* b1    = (const float*)d_in[4];
    const float* W2    = (const float*)d_in[5];
    const float* b2    = (const float*)d_in[6];
    const float* Wlab  = (const float*)d_in[7];
    const float* blab  = (const float*)d_in[8];
    const float* Wd1   = (const float*)d_in[9];
    const float* bd1   = (const float*)d_in[10];
    const float* Wd2   = (const float*)d_in[11];
    const float* bd2   = (const float*)d_in[12];
    float* out = (float*)d_out;

    const int N = in_sizes[0] / 16;
    const int E = in_sizes[1] / 2;
    const int G = out_size / 3;
    const int NB = (N + 255) >> 8;             // node buckets of 256

    char* p = (char*)d_ws;
    auto carve = [&](size_t bytes) {
        void* r = (void*)p;
        p += (bytes + 255) & ~(size_t)255;
        return r;
    };
    int*      bcnt   = (int*)     carve(256 * 4);
    unsigned* col1   = (unsigned*)carve((size_t)NB * BCAP * 4);
    int*      col    = (int*)     carve((size_t)E * 4);
    int*      rowptr = (int*)     carve((size_t)(N + 1) * 4);
    int*      gptr   = (int*)     carve((size_t)(G + 1) * 4);
    float*    dinv   = (float*)   carve((size_t)N * 4);
    unsigned short* xsb  = (unsigned short*)carve((size_t)N * 16 * 2);
    unsigned short* W2bf = (unsigned short*)carve(128 * 128 * 2);
    unsigned char*  ht1q = (unsigned char*) carve((size_t)N * 128);
    float*    gsum   = (float*)   carve((size_t)G * 128 * 4);

    const int FB = (E + TILE - 1) / TILE;      // bfill: one LDS tile/block

    hipMemsetAsync(bcnt, 0, 256 * 4, stream);
    k_bfill  <<<FB, 512, 0, stream>>>(ei, bcnt, col1, batch, gptr, gsum, W2,
                                      W2bf, E, NB, N, G);
    k_bsort  <<<NB, 512, 0, stream>>>(col1, bcnt, col, rowptr, dinv, x, xsb,
                                      N, E, NB);
    k_l12g   <<<(N + 63) / 64, 512, 0, stream>>>(rowptr, col, xsb, dinv,
                                                 W1, b1, W2bf, ht1q, N);
    k_gat128pool<<<(N + 7) / 8, 512, 0, stream>>>(rowptr, col, ht1q, dinv, b2,
                                                  batch, gsum, N);
    k_head   <<<G, 128, 0, stream>>>(gsum, gptr, Wlab, blab, Wd1, bd1, Wd2,
                                     bd2, out, G);
}

// Round 12
// 205.956 us; speedup vs baseline: 1.0611x; 1.0611x over previous
//
#include <hip/hip_runtime.h>
#include <hip/hip_fp16.h>
#include <math.h>

// GCN forward, CSR-gather; bf16 xs/W2; MFMA layer-2 dense; block-
// aggregated pooling. CSR build = single-pass fixed-capacity bucket sort.
// R12: REVERT gather to R10's 4-deep config (best: 208.3us total, gather
// 50.4us). R11's 8-deep pipeline regressed (62us, occ 65->51%): with
// loads ~10cy apart at issue, longer batches add serial segment length,
// not usable MLP. MLP lever now dead in BOTH regimes (R3 null at
// fetch-bound, R11 negative at latency-bound). Gather standing state:
// FETCH 51.5MB = compulsory floor (8 XCD x 6.4MB e5m2 table, R9); decode
// is HW v_cvt_pk_f32_bf8 (R10); VALU 33%/HBM 16%/occ 65% = issue/latency
// floor with no counter-visible lever left. Build kernels null to +-1us
// across R6/R8. Harness poison fill ~45us at HBM write peak (268MB).
// Requires N <= 65536 (src packed in 16 bits, bucket fits 8 bits).

#define BCAP 12288   // bucket capacity (mean fill ~8.2K, 45 sigma headroom)
#define TILE 8192    // bfill edges per block (LDS-staged, 64KB)

typedef __attribute__((ext_vector_type(8))) short short8;   // 8 bf16 (4 VGPRs)
typedef __attribute__((ext_vector_type(4))) float f32x4;    // MFMA accumulator
typedef __attribute__((ext_vector_type(2))) float f32x2;

__device__ __forceinline__ void bf4acc(uint2 u, float* a) {
    a[0] += __uint_as_float(u.x << 16);
    a[1] += __uint_as_float(u.x & 0xffff0000u);
    a[2] += __uint_as_float(u.y << 16);
    a[3] += __uint_as_float(u.y & 0xffff0000u);
}

__device__ __forceinline__ unsigned short bf1(float a) {    // RNE bf16
    unsigned ua = __float_as_uint(a);
    return (unsigned short)((ua + 0x7fffu + ((ua >> 16) & 1u)) >> 16);
}

__device__ __forceinline__ unsigned char e5m2q(float v) {   // RNE e5m2
    const unsigned hb = (unsigned)__half_as_ushort(__float2half(v));
    return (unsigned char)((hb + 0x7fu + ((hb >> 8) & 1u)) >> 8);
}

// decode 4 e5m2 bytes (features 4k..4k+3) and accumulate.
// bf8 (AMD) == e5m2 (OCP): HW cvt is bit-exact vs the fp16-top-byte trick.
__device__ __forceinline__ void e5acc(unsigned u, float* a) {
#if __has_builtin(__builtin_amdgcn_cvt_pk_f32_bf8)
    const f32x2 lo = __builtin_amdgcn_cvt_pk_f32_bf8((int)u, false);
    const f32x2 hi = __builtin_amdgcn_cvt_pk_f32_bf8((int)u, true);
    a[0] += lo[0]; a[1] += lo[1];
    a[2] += hi[0]; a[3] += hi[1];
#else
    unsigned h01 = ((u & 0x000000ffu) << 8) | ((u & 0x0000ff00u) << 16);
    unsigned h23 = ((u & 0x00ff0000u) >> 8) | (u & 0xff000000u);
    const __half2 x01 = *reinterpret_cast<const __half2*>(&h01);
    const __half2 x23 = *reinterpret_cast<const __half2*>(&h23);
    const float2 f01 = __half22float2(x01);
    const float2 f23 = __half22float2(x23);
    a[0] += f01.x; a[1] += f01.y;
    a[2] += f23.x; a[3] += f23.y;
#endif
}

// ---- LDS-staged bucketed fill: 8192-edge tile -> local counting sort ->
//      coalesced per-bucket run copy-out (~32 edges = 128B per run) ----
__global__ __launch_bounds__(512) void k_bfill(
        const int* __restrict__ ei, int* __restrict__ bcnt,
        unsigned* __restrict__ col1,
        const int* __restrict__ batch, int* __restrict__ gptr,
        float* __restrict__ gsum, const float* __restrict__ W2,
        unsigned short* __restrict__ W2bf,
        int E, int NB, int N, int G) {
    __shared__ unsigned ev[TILE];      // (b<<24)|(dstLocal<<16)|src
    __shared__ unsigned es[TILE];      // bucket-sorted
    __shared__ int bins[256], scn[256], cur[256], gbase[256];
    const int t = threadIdx.x;
    const int e0 = blockIdx.x * TILE;
    int cnt = E - e0; if (cnt > TILE) cnt = TILE;

    if (t < 256) bins[t] = 0;
    __syncthreads();
    for (int i = t; i < cnt; i += 512) {        // stage + histogram
        const int d = ei[E + e0 + i];
        const int s = ei[e0 + i];
        const unsigned b = (unsigned)d >> 8;    // NB <= 256 -> fits 8 bits
        ev[i] = (b << 24) | ((unsigned)(d & 255) << 16) | (unsigned)s;
        atomicAdd(&bins[b], 1);
    }
    __syncthreads();
    int v = 0;
    if (t < 256) { v = bins[t]; scn[t] = v; }
    __syncthreads();
    for (int off = 1; off < 256; off <<= 1) {   // inclusive scan (256-wide)
        int add = (t >= off && t < 256) ? scn[t - off] : 0;
        __syncthreads();
        if (t < 256) scn[t] += add;
        __syncthreads();
    }
    int ex = 0;
    if (t < 256) ex = scn[t] - v;
    __syncthreads();
    if (t < 256) {
        scn[t] = ex;                            // exclusive local offsets
        cur[t] = 0;
        gbase[t] = v ? atomicAdd(&bcnt[t], v) : 0;  // reserve global run
    }
    __syncthreads();
    for (int i = t; i < cnt; i += 512) {        // scatter within LDS
        const unsigned e = ev[i];
        const int b = e >> 24;
        const int p = scn[b] + atomicAdd(&cur[b], 1);
        es[p] = e;
    }
    __syncthreads();
    for (int i = t; i < cnt; i += 512) {        // coalesced copy-out
        const unsigned e = es[i];
        const int b = e >> 24;
        const int pos = gbase[b] + (i - scn[b]);
        if (pos < BCAP)
            col1[(size_t)b * BCAP + pos] = e & 0xffffffu;
    }

    // distributed prep tails
    const int gid = blockIdx.x * 512 + t;
    const int gsz = gridDim.x * 512;
    for (int i = gid; i < G * 32; i += gsz)        // gsum = 0 (float4)
        ((float4*)gsum)[i] = make_float4(0.f, 0.f, 0.f, 0.f);
    for (int i = gid; i < 16384; i += gsz) {       // W2bf[f2][f1] = bf16(W2[f1][f2])
        const int f2 = i >> 7, f1 = i & 127;
        W2bf[i] = bf1(W2[f1 * 128 + f2]);
    }
    for (int g = gid; g <= G; g += gsz) {          // gptr = lower_bound(batch,g)
        int lo = 0, hi = N;
        while (lo < hi) {
            int mid = (lo + hi) >> 1;
            if (batch[mid] < g) lo = mid + 1; else hi = mid;
        }
        gptr[g] = lo;
    }
}

// ---- per-bucket LDS sort -> exact CSR + dinv + xsb (self-scans bcnt) ----
__global__ __launch_bounds__(512) void k_bsort(const unsigned* __restrict__ col1,
                                               const int* __restrict__ bcnt,
                                               int* __restrict__ col,
                                               int* __restrict__ rowptr,
                                               float* __restrict__ dinv,
                                               const float* __restrict__ x,
                                               unsigned short* __restrict__ xsb,
                                               int N, int E, int NB) {
    __shared__ unsigned ec[BCAP];
    __shared__ int bins[256], sc[256];
    __shared__ float dvb[256];
    const int b = blockIdx.x, t = threadIdx.x;

    // bucket-offset scan (196 ints, L2-hot): s0 = sum_{i<b} bcnt[i]
    if (t < 256) bins[t] = (t < NB) ? bcnt[t] : 0;
    __syncthreads();
    for (int off = 1; off < 256; off <<= 1) {
        int add = (t >= off && t < 256) ? bins[t - off] : 0;
        __syncthreads();
        if (t < 256) bins[t] += add;
        __syncthreads();
    }
    const int s0 = (b == 0) ? 0 : bins[b - 1];
    int cnt = bcnt[b];
    if (cnt > BCAP) cnt = BCAP;        // safety clamp (never hit for this E,N)
    __syncthreads();

    for (int i = t; i < cnt; i += 512) ec[i] = col1[(size_t)b * BCAP + i];
    if (t < 256) bins[t] = 0;
    __syncthreads();
    for (int i = t; i < cnt; i += 512) atomicAdd(&bins[ec[i] >> 16], 1);
    __syncthreads();
    int v = 0;
    if (t < 256) { v = bins[t]; sc[t] = v; }
    __syncthreads();
    for (int off = 1; off < 256; off <<= 1) {
        int add = (t >= off && t < 256) ? sc[t - off] : 0;
        __syncthreads();
        if (t < 256) sc[t] += add;
        __syncthreads();
    }
    int ex = 0;
    if (t < 256) ex = sc[t] - v;
    __syncthreads();
    const int n0 = b * 256;
    if (t < 256) {
        sc[t] = ex;          // exclusive local offsets
        bins[t] = 0;         // reuse as per-node cursor
        const float dv = rsqrtf((float)(v + 1));
        dvb[t] = dv;
        if (n0 + t < N) {
            rowptr[n0 + t] = s0 + ex;
            dinv[n0 + t] = dv;
        }
    }
    if (b == 0 && t == 0) rowptr[N] = E;
    __syncthreads();
    for (int i = t; i < cnt; i += 512) {
        unsigned e = ec[i];
        int dl = e >> 16;
        int p = sc[dl] + atomicAdd(&bins[dl], 1);
        col[s0 + p] = (int)(e & 0xffffu);
    }
    // xsb = bf16(x * dinv) for this bucket's nodes (coalesced)
    int nn = N - n0; if (nn > 256) nn = 256;
    const int lim = nn * 16;
    for (int i = t; i < lim; i += 512) {
        float vx = x[(size_t)n0 * 16 + i] * dvb[i >> 4];
        xsb[(size_t)n0 * 16 + i] = bf1(vx);
    }
}

// ---- FUSED gat16 + l12 (MFMA): 64 nodes/block, 512 threads (8 waves),
//      ~57 KB LDS -> 2 blocks/CU. Epilogue stores ht1 as e5m2 bytes.
__global__ __launch_bounds__(512, 4) void k_l12g(
        const int* __restrict__ rowptr, const int* __restrict__ col,
        const unsigned short* __restrict__ xsb,
        const float* __restrict__ dinv,
        const float* __restrict__ W1, const float* __restrict__ b1,
        const unsigned short* __restrict__ W2bf,   // [f2][f1] bf16
        unsigned char* __restrict__ ht1q, int N) {
    __shared__ __align__(16) unsigned short W2s[128 * 136];  // [f2][f1] padded
    __shared__ __align__(16) unsigned short h1b[64 * 136];   // [node][f1] padded
    __shared__ __align__(16) float arow[64 * 16];
    __shared__ float dv[64];
    const int tid = threadIdx.x;
    const int n0 = blockIdx.x * 64;
    const int w = tid >> 6, lane = tid & 63;

    // stage W2^T (bf16): 128 rows x 16 uint4 segments
    for (int i = tid; i < 2048; i += 512) {
        const int f2 = i >> 4, seg = i & 15;
        *(uint4*)&W2s[f2 * 136 + seg * 8] = ((const uint4*)W2bf)[i];
    }
    if (tid < 64) dv[tid] = (n0 + tid < N) ? dinv[n0 + tid] : 0.f;

    // gather: 8 lanes per node (2 edge slots x 4 quarters), 8 nodes per wave
    {
        const int nd = lane >> 3, sub = lane & 7;
        const int slot = sub >> 2, qq = sub & 3;
        const int j = w * 8 + nd;
        const int n = n0 + j;
        float a[4] = {0.f, 0.f, 0.f, 0.f};
        if (n < N) {
            const int r1 = rowptr[n + 1];
            for (int e = rowptr[n] + slot; e < r1; e += 2)
                bf4acc(*(const uint2*)(xsb + (size_t)col[e] * 16 + qq * 4), a);
        }
#pragma unroll
        for (int i = 0; i < 4; ++i) a[i] += __shfl_xor(a[i], 4);
        if (slot == 0) {
            if (n < N) {   // self loop
                bf4acc(*(const uint2*)(xsb + (size_t)n * 16 + qq * 4), a);
                *(float4*)&arow[j * 16 + qq * 4] = make_float4(a[0], a[1], a[2], a[3]);
            } else {
                *(float4*)&arow[j * 16 + qq * 4] = make_float4(0.f, 0.f, 0.f, 0.f);
            }
        }
    }
    const int f = tid & 127, jg = tid >> 7;
    float w1r[16];
#pragma unroll
    for (int k = 0; k < 16; ++k) w1r[k] = W1[k * 128 + f];
    const float bias = b1[f];
    __syncthreads();

    // phase 1: h1 (bf16) into A-layout LDS
#pragma unroll 4
    for (int j = jg * 16; j < jg * 16 + 16; ++j) {
        float s = 0.f;
#pragma unroll
        for (int k = 0; k < 16; ++k) s += arow[j * 16 + k] * w1r[k];
        h1b[j * 136 + f] = bf1(fmaxf(dv[j] * s + bias, 0.f));
    }
    __syncthreads();

    // phase 2: MFMA, D[64x128] = h1[64x128] @ W2[128x128]
    const int mt = w & 3, nh = w >> 2;
    const int lm = lane & 15, quad = lane >> 4;
    f32x4 acc[4];
#pragma unroll
    for (int t = 0; t < 4; ++t) acc[t] = (f32x4){0.f, 0.f, 0.f, 0.f};
#pragma unroll
    for (int kb = 0; kb < 4; ++kb) {
        const short8 af = *(const short8*)&h1b[(mt * 16 + lm) * 136 + kb * 32 + quad * 8];
#pragma unroll
        for (int t = 0; t < 4; ++t) {
            const short8 bfv = *(const short8*)&W2s[(nh * 64 + t * 16 + lm) * 136 + kb * 32 + quad * 8];
            acc[t] = __builtin_amdgcn_mfma_f32_16x16x32_bf16(af, bfv, acc[t], 0, 0, 0);
        }
    }
    // epilogue: *dinv, quantize e5m2, store bytes
#pragma unroll
    for (int t = 0; t < 4; ++t) {
        const int f2 = nh * 64 + t * 16 + lm;
#pragma unroll
        for (int r = 0; r < 4; ++r) {
            const int j = mt * 16 + quad * 4 + r;
            const int n = n0 + j;
            if (n < N)
                ht1q[(size_t)n * 128 + f2] = e5m2q(acc[t][r] * dv[j]);
        }
    }
}

// Wave/node gather (2 halves x 32 lanes x uint(4 e5m2), 4x unroll -> 8
// rows in flight), then 8-node LDS run-merge (batch sorted) -> ~1 atomic
// set/block. Row = 128B e5m2; lane offset hoisted into hb.
__global__ __launch_bounds__(512) void k_gat128pool(
        const int* __restrict__ rowptr, const int* __restrict__ col,
        const unsigned char* __restrict__ ht1q,
        const float* __restrict__ dinv, const float* __restrict__ b2,
        const int* __restrict__ batch, float* __restrict__ gsum, int N) {
    __shared__ __align__(16) float h2s[8][128];
    __shared__ int bats[8];
    const int wave = threadIdx.x >> 6, lane = threadIdx.x & 63;
    const int half = lane >> 5, q = lane & 31;
    const int n = blockIdx.x * 8 + wave;
    const unsigned char* hb = ht1q + q * 4;    // lane's 4B column, hoisted
    float a[4] = {0.f, 0.f, 0.f, 0.f};
    if (n < N) {
        const int r0 = rowptr[n], r1 = rowptr[n + 1];
        int j = r0 + half;
        while (j + 6 < r1) {
            int s0 = col[j], s1 = col[j + 2], s2 = col[j + 4], s3 = col[j + 6];
            unsigned u0 = *(const unsigned*)(hb + ((size_t)s0 << 7));
            unsigned u1 = *(const unsigned*)(hb + ((size_t)s1 << 7));
            unsigned u2 = *(const unsigned*)(hb + ((size_t)s2 << 7));
            unsigned u3 = *(const unsigned*)(hb + ((size_t)s3 << 7));
            e5acc(u0, a); e5acc(u1, a); e5acc(u2, a); e5acc(u3, a);
            j += 8;
        }
        while (j < r1) {
            e5acc(*(const unsigned*)(hb + ((size_t)col[j] << 7)), a);
            j += 2;
        }
        if (half == 0)  // self loop
            e5acc(*(const unsigned*)(hb + ((size_t)n << 7)), a);
    }
#pragma unroll
    for (int i = 0; i < 4; ++i) a[i] += __shfl_xor(a[i], 32);
    if (half == 0) {
        if (n < N) {
            const float d = dinv[n];
            const float4 bb = *(const float4*)(b2 + q * 4);
            h2s[wave][q * 4 + 0] = fmaxf(a[0] * d + bb.x, 0.f);
            h2s[wave][q * 4 + 1] = fmaxf(a[1] * d + bb.y, 0.f);
            h2s[wave][q * 4 + 2] = fmaxf(a[2] * d + bb.z, 0.f);
            h2s[wave][q * 4 + 3] = fmaxf(a[3] * d + bb.w, 0.f);
            if (q == 0) bats[wave] = batch[n];
        } else {
            h2s[wave][q * 4 + 0] = 0.f; h2s[wave][q * 4 + 1] = 0.f;
            h2s[wave][q * 4 + 2] = 0.f; h2s[wave][q * 4 + 3] = 0.f;
            if (q == 0) bats[wave] = -1;
        }
    }
    __syncthreads();
    if (threadIdx.x < 32) {
        const int qq = threadIdx.x;
        int bprev = bats[0];
        float4 acc4 = *(const float4*)&h2s[0][qq * 4];
#pragma unroll
        for (int wv = 1; wv < 8; ++wv) {
            const int bw = bats[wv];   // wave-uniform branch (LDS scalar)
            const float4 rv = *(const float4*)&h2s[wv][qq * 4];
            if (bw == bprev) {
                acc4.x += rv.x; acc4.y += rv.y; acc4.z += rv.z; acc4.w += rv.w;
            } else {
                if (bprev >= 0) {
                    float* gs = gsum + (size_t)bprev * 128 + qq * 4;
                    unsafeAtomicAdd(gs + 0, acc4.x); unsafeAtomicAdd(gs + 1, acc4.y);
                    unsafeAtomicAdd(gs + 2, acc4.z); unsafeAtomicAdd(gs + 3, acc4.w);
                }
                bprev = bw; acc4 = rv;
            }
        }
        if (bprev >= 0) {
            float* gs = gsum + (size_t)bprev * 128 + qq * 4;
            unsafeAtomicAdd(gs + 0, acc4.x); unsafeAtomicAdd(gs + 1, acc4.y);
            unsafeAtomicAdd(gs + 2, acc4.z); unsafeAtomicAdd(gs + 3, acc4.w);
        }
    }
}

__global__ __launch_bounds__(128) void k_head(
        const float* __restrict__ gsum, const int* __restrict__ gptr,
        const float* __restrict__ Wlab, const float* __restrict__ blab,
        const float* __restrict__ Wd1, const float* __restrict__ bd1,
        const float* __restrict__ Wd2, const float* __restrict__ bd2,
        float* __restrict__ out, int G) {
    __shared__ float sp[128];
    __shared__ float red[128];
    __shared__ float hd[64];
    const int g = blockIdx.x, t = threadIdx.x;
    const float cnt = (float)(gptr[g + 1] - gptr[g]);
    const float invc = 1.f / fmaxf(cnt, 1.f);
    const float pooled = gsum[g * 128 + t] * invc;
    sp[t] = pooled;
    red[t] = pooled * Wlab[t];
    __syncthreads();
    for (int off = 64; off > 0; off >>= 1) {
        if (t < off) red[t] += red[t + off];
        __syncthreads();
    }
    if (t == 0) out[g] = 1.f / (1.f + expf(-(red[0] + blab[0])));
    __syncthreads();   // red[] reuse barrier (label reduce fully consumed)
    // domain hidden: 2-way split-K across all 128 threads
    const int tt = t & 63, kh = t >> 6;
    const int f0 = kh * 64;
    float ps = 0.f;
#pragma unroll 8
    for (int f = f0; f < f0 + 64; ++f) ps += sp[f] * Wd1[f * 64 + tt];
    red[t] = ps;
    __syncthreads();
    if (t < 64) hd[t] = fmaxf(red[t] + red[t + 64] + bd1[t], 0.f);
    __syncthreads();
    if (t < 2) {
        float s = bd2[t];
        for (int j = 0; j < 64; ++j) s += hd[j] * Wd2[j * 2 + t];
        out[G + g * 2 + t] = s;
    }
}

extern "C" void kernel_launch(void* const* d_in, const int* in_sizes, int n_in,
                              void* d_out, int out_size, void* d_ws, size_t ws_size,
                              hipStream_t stream) {
    const float* x     = (const float*)d_in[0];
    const int*   ei    = (const int*)d_in[1];   // [2,E]: ei[e]=src, ei[E+e]=dst
    const int*   batch = (const int*)d_in[2];
    const float* W1    = (const float*)d_in[3];
    const float* b1    = (const float*)d_in[4];
    const float* W2    = (const float*)d_in[5];
    const float* b2    = (const float*)d_in[6];
    const float* Wlab  = (const float*)d_in[7];
    const float* blab  = (const float*)d_in[8];
    const float* Wd1   = (const float*)d_in[9];
    const float* bd1   = (const float*)d_in[10];
    const float* Wd2   = (const float*)d_in[11];
    const float* bd2   = (const float*)d_in[12];
    float* out = (float*)d_out;

    const int N = in_sizes[0] / 16;
    const int E = in_sizes[1] / 2;
    const int G = out_size / 3;
    const int NB = (N + 255) >> 8;             // node buckets of 256

    char* p = (char*)d_ws;
    auto carve = [&](size_t bytes) {
        void* r = (void*)p;
        p += (bytes + 255) & ~(size_t)255;
        return r;
    };
    int*      bcnt   = (int*)     carve(256 * 4);
    unsigned* col1   = (unsigned*)carve((size_t)NB * BCAP * 4);
    int*      col    = (int*)     carve((size_t)E * 4);
    int*      rowptr = (int*)     carve((size_t)(N + 1) * 4);
    int*      gptr   = (int*)     carve((size_t)(G + 1) * 4);
    float*    dinv   = (float*)   carve((size_t)N * 4);
    unsigned short* xsb  = (unsigned short*)carve((size_t)N * 16 * 2);
    unsigned short* W2bf = (unsigned short*)carve(128 * 128 * 2);
    unsigned char*  ht1q = (unsigned char*) carve((size_t)N * 128);
    float*    gsum   = (float*)   carve((size_t)G * 128 * 4);

    const int FB = (E + TILE - 1) / TILE;      // bfill: one LDS tile/block

    hipMemsetAsync(bcnt, 0, 256 * 4, stream);
    k_bfill  <<<FB, 512, 0, stream>>>(ei, bcnt, col1, batch, gptr, gsum, W2,
                                      W2bf, E, NB, N, G);
    k_bsort  <<<NB, 512, 0, stream>>>(col1, bcnt, col, rowptr, dinv, x, xsb,
                                      N, E, NB);
    k_l12g   <<<(N + 63) / 64, 512, 0, stream>>>(rowptr, col, xsb, dinv,
                                                 W1, b1, W2bf, ht1q, N);
    k_gat128pool<<<(N + 7) / 8, 512, 0, stream>>>(rowptr, col, ht1q, dinv, b2,
                                                  batch, gsum, N);
    k_head   <<<G, 128, 0, stream>>>(gsum, gptr, Wlab, blab, Wd1, bd1, Wd2,
                                     bd2, out, G);
}